// Round 5
// baseline (45.183 us; speedup 1.0000x reference)
//
#include <hip/hip_runtime.h>
#include <hip/hip_bf16.h>
#include <math.h>

#define BB 2
#define TT 2048
#define CC 256
#define HH 4
#define DD 64
#define WW 64
#define TQ 2047
#define N_KQV 768

typedef __attribute__((ext_vector_type(8))) short bf16x8;
typedef __attribute__((ext_vector_type(4))) float f32x4;

__device__ inline short f2bf(float x) {
    unsigned u = __float_as_uint(x);
    u += 0x7FFF + ((u >> 16) & 1);
    return (short)(u >> 16);
}
__device__ inline float bf2f(short s) {
    return __uint_as_float(((unsigned)(unsigned short)s) << 16);
}
__device__ inline bf16x8 cvt8(float4 a, float4 b) {
    bf16x8 r;
    r[0] = f2bf(a.x); r[1] = f2bf(a.y); r[2] = f2bf(a.z); r[3] = f2bf(a.w);
    r[4] = f2bf(b.x); r[5] = f2bf(b.y); r[6] = f2bf(b.z); r[7] = f2bf(b.w);
    return r;
}

// ---------------------------------------------------------------------------
// bf16-MFMA GEMM: C[M,N] = A[M,K] @ B[N,K]^T (+bias).  BK=64.
// ABF: A is bf16 (else f32, converted in staging). BBF: B is bf16.
// CBF: C stored bf16.  ZROW: rows with (m % 2048)==0 read as zero.
// CONV: blocks with blockIdx.x==gridDim.x-1 convert q_pos/v_pos/w_out to bf16
//       (runs concurrently with the GEMM blocks; consumed by later kernels).
// ---------------------------------------------------------------------------
template<bool ABF, bool BBF, int BM, int BN, int WR, int WC,
         bool ZROW, bool BIAS, bool CBF, bool CONV>
__global__ __launch_bounds__(256)
void gemm_mfma(const void* __restrict__ Av, const void* __restrict__ Bv,
               const float* __restrict__ bias, void* __restrict__ Cv,
               int M, int N, int K,
               const float* __restrict__ qposf, const float* __restrict__ vposf,
               const float* __restrict__ woutf,
               short* __restrict__ qposb, short* __restrict__ vposTb,
               short* __restrict__ woutb) {
    constexpr int BK = 64;
    constexpr int LDA = BK + 8;
    constexpr int MR = BM / (WR * 16);
    constexpr int NR = BN / (WC * 16);
    __shared__ short As[BM][LDA];
    __shared__ short Bs[BN][LDA];

    const int tid = threadIdx.x;

    if (CONV && (int)blockIdx.x == (int)gridDim.x - 1) {
        // 8 converter blocks (by blockIdx.y): 98304 elements total
        const int base = blockIdx.y * 12288;
#pragma unroll
        for (int i = 0; i < 48; ++i) {
            int e = base + i * 256 + tid;
            if (e < 65536) {
                woutb[e] = f2bf(woutf[e]);
            } else if (e < 81920) {
                int e2 = e - 65536;
                int h = e2 >> 12, r = e2 & 4095, w = r >> 6, d = r & 63;
                qposb[e2] = f2bf(qposf[(w * HH + h) * DD + d]);
            } else {
                int e3 = e - 81920;
                int h = e3 >> 12, r = e3 & 4095, d = r >> 6, w = r & 63;
                vposTb[e3] = f2bf(vposf[(w * HH + h) * DD + d]);
            }
        }
        return;
    }

    const int m0 = blockIdx.x * BM, n0 = blockIdx.y * BN;
    const int wv = tid >> 6, lane = tid & 63;
    const int wr = wv / WC, wc = wv % WC;
    const int col = lane & 15, kg = lane >> 4;

    f32x4 acc[MR][NR];
#pragma unroll
    for (int i = 0; i < MR; ++i)
#pragma unroll
        for (int j = 0; j < NR; ++j) acc[i][j] = (f32x4){0.f, 0.f, 0.f, 0.f};

    for (int k0 = 0; k0 < K; k0 += BK) {
#pragma unroll
        for (int it = 0; it < BM / 32; ++it) {
            int fi = tid + it * 256;
            int r = fi >> 3, c8 = (fi & 7) << 3;
            int gr = m0 + r;
            bf16x8 sv;
            if (ZROW && ((gr & (TT - 1)) == 0)) {
                sv = (bf16x8){0, 0, 0, 0, 0, 0, 0, 0};
            } else if constexpr (ABF) {
                sv = *reinterpret_cast<const bf16x8*>(
                    (const short*)Av + (size_t)gr * K + k0 + c8);
            } else {
                const float* ap = (const float*)Av + (size_t)gr * K + k0 + c8;
                float4 v0 = *reinterpret_cast<const float4*>(ap);
                float4 v1 = *reinterpret_cast<const float4*>(ap + 4);
                sv = cvt8(v0, v1);
            }
            *reinterpret_cast<bf16x8*>(&As[r][c8]) = sv;
        }
#pragma unroll
        for (int it = 0; it < BN / 32; ++it) {
            int fi = tid + it * 256;
            int r = fi >> 3, c8 = (fi & 7) << 3;
            bf16x8 sv;
            if constexpr (BBF) {
                sv = *reinterpret_cast<const bf16x8*>(
                    (const short*)Bv + (size_t)(n0 + r) * K + k0 + c8);
            } else {
                const float* bp = (const float*)Bv + (size_t)(n0 + r) * K + k0 + c8;
                float4 v0 = *reinterpret_cast<const float4*>(bp);
                float4 v1 = *reinterpret_cast<const float4*>(bp + 4);
                sv = cvt8(v0, v1);
            }
            *reinterpret_cast<bf16x8*>(&Bs[r][c8]) = sv;
        }
        __syncthreads();

#pragma unroll
        for (int kk = 0; kk < 2; ++kk) {
            bf16x8 af[MR], bfr[NR];
#pragma unroll
            for (int i = 0; i < MR; ++i)
                af[i] = *reinterpret_cast<const bf16x8*>(
                    &As[wr * MR * 16 + i * 16 + col][kk * 32 + kg * 8]);
#pragma unroll
            for (int j = 0; j < NR; ++j)
                bfr[j] = *reinterpret_cast<const bf16x8*>(
                    &Bs[wc * NR * 16 + j * 16 + col][kk * 32 + kg * 8]);
#pragma unroll
            for (int i = 0; i < MR; ++i)
#pragma unroll
                for (int j = 0; j < NR; ++j)
                    acc[i][j] = __builtin_amdgcn_mfma_f32_16x16x32_bf16(
                        af[i], bfr[j], acc[i][j], 0, 0, 0);
        }
        __syncthreads();
    }

#pragma unroll
    for (int i = 0; i < MR; ++i) {
#pragma unroll
        for (int j = 0; j < NR; ++j) {
#pragma unroll
            for (int r = 0; r < 4; ++r) {
                int m = m0 + wr * MR * 16 + i * 16 + kg * 4 + r;
                int n = n0 + wc * NR * 16 + j * 16 + col;
                float v = acc[i][j][r];
                if (BIAS) v += bias[n];
                if constexpr (CBF)
                    ((short*)Cv)[(size_t)m * N + n] = f2bf(v);
                else
                    ((float*)Cv)[(size_t)m * N + n] = v;
            }
        }
    }
}

// ---------------------------------------------------------------------------
// Fused attention, one block per (b, h, 16-row t tile): 1024 blocks, 4 waves.
//   scores(t,w) = 0.125*(dq[j] + qq[j,w]),  j = t-63+w, j_local jl = (t-t0)+w.
//   qq via MFMA with A-frags direct from global q; dq via 158-thread dot pass.
//   softmax: 16 rows, one per 16-lane group.  PV via MFMA (banded P' against
//   LDS-transposed V, dense P against preconverted v_posT).
// ---------------------------------------------------------------------------
__global__ __launch_bounds__(256)
void attn_fused(const short* __restrict__ kqvb, const short* __restrict__ qposb,
                const short* __restrict__ vposTb, float* __restrict__ wei_out,
                short* __restrict__ attnSb) {
    __shared__ __align__(16) short VT[64 * 104];   // [d][jl], jl 0..95 (79 valid)
    __shared__ __align__(16) short PP[16 * 104];   // banded P', K=96
    __shared__ __align__(16) short PD[16 * 72];    // dense P, K=64
    __shared__ float SB[16 * 68];                  // raw qq scores
    __shared__ float DQ[80];                       // k.q per j_local

    const int tid  = threadIdx.x;
    const int wv   = tid >> 6;
    const int lane = tid & 63;
    const int col  = lane & 15;
    const int kg   = lane >> 4;
    const int bid  = blockIdx.x;
    const int tile = bid & 127;
    const int h    = (bid >> 7) & 3;
    const int b    = bid >> 9;
    const int t0   = tile * 16;
    const int j0   = t0 - 63;

    // ---- zero PP (pads must be 0; band overwritten later)
    {
        unsigned int* pz = reinterpret_cast<unsigned int*>(PP);
#pragma unroll
        for (int i = 0; i < 4; ++i) {
            int fi = tid + i * 256;
            if (fi < 832) pz[fi] = 0u;
        }
    }

    // ---- dq: k[j].q[j] for jl = 0..78 (2 threads per row, 32 d each)
    if (tid < 158) {
        int row = tid >> 1, half = tid & 1;
        int j = j0 + row;
        float s = 0.f;
        if (j >= 0) {
            const short* kp = kqvb + ((size_t)(b * TT + j)) * N_KQV + h * DD + half * 32;
            const short* qp = kp + 256;
#pragma unroll
            for (int c = 0; c < 32; c += 8) {
                bf16x8 kv = *reinterpret_cast<const bf16x8*>(kp + c);
                bf16x8 qv = *reinterpret_cast<const bf16x8*>(qp + c);
#pragma unroll
                for (int q = 0; q < 8; ++q) s += bf2f(kv[q]) * bf2f(qv[q]);
            }
        }
        s += __shfl_xor(s, 1);
        if (half == 0) DQ[row] = s;
    }

    // ---- stage V transposed: VT[d][jl], rows jl 0..95 (zero beyond 78)
#pragma unroll
    for (int it = 0; it < 3; ++it) {
        int fi = tid + it * 256;                 // 0..767 = 96 rows x 8 chunks
        int r = fi >> 3, c = fi & 7, c8 = c << 3;
        int j = j0 + r;
        bf16x8 v = (bf16x8){0, 0, 0, 0, 0, 0, 0, 0};
        if (r < 79 && j >= 0)
            v = *reinterpret_cast<const bf16x8*>(
                kqvb + ((size_t)(b * TT + j)) * N_KQV + 512 + h * DD + c8);
        // rotated write order: per-slot d = c8 + ((q0+c)&7) spreads banks
#pragma unroll
        for (int q0 = 0; q0 < 8; ++q0) {
            int qp = (q0 + c) & 7;
            VT[(c8 + qp) * 104 + r] = v[qp];
        }
    }

    // ---- qq MFMA: wave wv does m-tile wv (wave 0 also m-tile 4)
    f32x4 qa[2][4];
#pragma unroll
    for (int im = 0; im < 2; ++im)
#pragma unroll
        for (int n = 0; n < 4; ++n) qa[im][n] = (f32x4){0.f, 0.f, 0.f, 0.f};
    const int nmt = (wv == 0) ? 2 : 1;
    for (int im = 0; im < nmt; ++im) {
        int mt = im ? 4 : wv;
#pragma unroll
        for (int ks = 0; ks < 2; ++ks) {
            int jr = j0 + mt * 16 + col;
            bf16x8 af = (bf16x8){0, 0, 0, 0, 0, 0, 0, 0};
            if (jr >= 0)
                af = *reinterpret_cast<const bf16x8*>(
                    kqvb + ((size_t)(b * TT + jr)) * N_KQV + 256 + h * DD + ks * 32 + kg * 8);
#pragma unroll
            for (int n = 0; n < 4; ++n) {
                bf16x8 bfr = *reinterpret_cast<const bf16x8*>(
                    qposb + h * 4096 + (n * 16 + col) * 64 + ks * 32 + kg * 8);
                qa[im][n] = __builtin_amdgcn_mfma_f32_16x16x32_bf16(af, bfr, qa[im][n], 0, 0, 0);
            }
        }
    }
    // scatter band into SB
    for (int im = 0; im < nmt; ++im) {
        int mt = im ? 4 : wv;
#pragma unroll
        for (int n = 0; n < 4; ++n) {
            int w = n * 16 + col;
#pragma unroll
            for (int r = 0; r < 4; ++r) {
                int jl = mt * 16 + kg * 4 + r;
                int il = jl - w;
                if (il >= 0 && il < 16) SB[il * 68 + w] = qa[im][n][r];
            }
        }
    }
    __syncthreads();

    // ---- softmax: row per 16-lane group
    {
        const int row = wv * 4 + kg;
        const int wg  = col;
        const int t   = t0 + row;
        f32x4 sv = *reinterpret_cast<const f32x4*>(&SB[row * 68 + wg * 4]);
        float s4[4];
#pragma unroll
        for (int q = 0; q < 4; ++q) {
            int w = wg * 4 + q;
            float s = (sv[q] + DQ[row + w]) * 0.125f;
            if (tile < 4 && (j0 + row + w) < 0) s = -INFINITY;
            s4[q] = s;
        }
        float m = fmaxf(fmaxf(s4[0], s4[1]), fmaxf(s4[2], s4[3]));
#pragma unroll
        for (int off = 8; off; off >>= 1) m = fmaxf(m, __shfl_xor(m, off));
        float p[4], sum = 0.f;
#pragma unroll
        for (int q = 0; q < 4; ++q) { p[q] = __expf(s4[q] - m); sum += p[q]; }
#pragma unroll
        for (int off = 8; off; off >>= 1) sum += __shfl_xor(sum, off);
        float inv = 1.f / sum;
#pragma unroll
        for (int q = 0; q < 4; ++q) {
            int w = wg * 4 + q;
            float wei = p[q] * inv;
            if (t < TQ)
                wei_out[(((size_t)b * TQ + t) * WW + w) * HH + h] = wei;
            short wb = f2bf(wei);
            PD[row * 72 + w] = wb;
            PP[row * 104 + row + w] = wb;
        }
    }
    __syncthreads();

    // ---- PV MFMA: wave wv owns d-tile wv
    f32x4 pa = (f32x4){0.f, 0.f, 0.f, 0.f};
#pragma unroll
    for (int ks = 0; ks < 3; ++ks) {
        bf16x8 af = *reinterpret_cast<const bf16x8*>(&PP[col * 104 + ks * 32 + kg * 8]);
        bf16x8 bfr = *reinterpret_cast<const bf16x8*>(
            &VT[(wv * 16 + col) * 104 + ks * 32 + kg * 8]);
        pa = __builtin_amdgcn_mfma_f32_16x16x32_bf16(af, bfr, pa, 0, 0, 0);
    }
#pragma unroll
    for (int ks = 0; ks < 2; ++ks) {
        bf16x8 af = *reinterpret_cast<const bf16x8*>(&PD[col * 72 + ks * 32 + kg * 8]);
        bf16x8 bfr = *reinterpret_cast<const bf16x8*>(
            vposTb + h * 4096 + (wv * 16 + col) * 64 + ks * 32 + kg * 8);
        pa = __builtin_amdgcn_mfma_f32_16x16x32_bf16(af, bfr, pa, 0, 0, 0);
    }
#pragma unroll
    for (int r = 0; r < 4; ++r) {
        int t = t0 + kg * 4 + r;
        if (t < TQ)
            attnSb[((size_t)(b * TT) + t + 1) * CC + h * DD + wv * 16 + col] = f2bf(pa[r]);
    }
}

// ---------------------------------------------------------------------------
extern "C" void kernel_launch(void* const* d_in, const int* in_sizes, int n_in,
                              void* d_out, int out_size, void* d_ws, size_t ws_size,
                              hipStream_t stream) {
    const float* x     = (const float*)d_in[0];
    const float* w_kqv = (const float*)d_in[1];
    const float* w_out = (const float*)d_in[2];
    const float* b_out = (const float*)d_in[3];
    const float* q_pos = (const float*)d_in[4];
    const float* v_pos = (const float*)d_in[5];

    float* y   = (float*)d_out;
    float* wei = (float*)d_out + (size_t)BB * TT * CC;

    short* kqvb   = (short*)d_ws;                          // bf16 (B*T, 768)
    short* woutb  = kqvb + (size_t)BB * TT * N_KQV;        // bf16 (256,256)
    short* qposb  = woutb + 65536;                         // bf16 [h][w][d]
    short* vposTb = qposb + 16384;                         // bf16 [h][d][w]
    short* attnSb = vposTb + 16384;                        // bf16 (B*T, 256)

    // K1: kqv = x @ w_kqv^T (bf16 MFMA, bf16 out) + side conversions
    gemm_mfma<false, false, 64, 96, 2, 2, false, false, true, true>
        <<<dim3((BB * TT) / 64 + 1, N_KQV / 96), 256, 0, stream>>>(
            x, w_kqv, nullptr, kqvb, BB * TT, N_KQV, CC,
            q_pos, v_pos, w_out, qposb, vposTb, woutb);

    // K2: fused scores + softmax + PV, 1024 blocks
    attn_fused<<<BB * HH * 128, 256, 0, stream>>>(kqvb, qposb, vposTb, wei, attnSb);

    // K3: y = attnS @ w_out^T + b_out (bf16 A and B, f32 out, t==0 rows zero)
    gemm_mfma<true, true, 32, 64, 2, 2, true, true, false, false>
        <<<dim3((BB * TT) / 32, CC / 64), 256, 0, stream>>>(
            attnSb, woutb, b_out, y, BB * TT, CC, CC,
            nullptr, nullptr, nullptr, nullptr, nullptr, nullptr);
}